// Round 4
// baseline (133.409 us; speedup 1.0000x reference)
//
#include <hip/hip_runtime.h>
#include <hip/hip_cooperative_groups.h>
#include <stdint.h>

namespace cg = cooperative_groups;

#define B_ 16
#define L_ 256
#define D_ 1024
#define R_ 128
#define M_ (B_*L_)   // 4096 rows of t

typedef short short8 __attribute__((ext_vector_type(8)));
typedef float f32x4 __attribute__((ext_vector_type(4)));

__device__ __forceinline__ unsigned short f2bf(float f) {
  union { float f; unsigned int u; } v; v.f = f;
  unsigned int r = v.u + 0x7FFFu + ((v.u >> 16) & 1u);  // RNE
  return (unsigned short)(r >> 16);
}
__device__ __forceinline__ float bf2f(unsigned short s) {
  union { unsigned int u; float f; } v; v.u = ((unsigned int)s) << 16;
  return v.f;
}
__device__ __forceinline__ void gload_lds16(const void* g, void* l) {
  __builtin_amdgcn_global_load_lds(
      (const __attribute__((address_space(1))) unsigned int*)g,
      (__attribute__((address_space(3))) unsigned int*)l, 16, 0, 0);
}

// One cooperative kernel, three phases separated by grid.sync():
//   A: P [1024][128] f32 -> PbT [128][1024] bf16       (transpose+cast)
//   B: T = X @ P   (bf16 MFMA, BM=16/BN=64/BK=128, dbuf)
//   C: per-batch Gram + distance epilogue (2 tiles/block)
__global__ __launch_bounds__(256) void fused_all(
    const float* __restrict__ X, const float* __restrict__ P,
    float* __restrict__ Out, unsigned short* __restrict__ PbT,
    unsigned short* __restrict__ Tb) {
  cg::grid_group grid = cg::this_grid();

  __shared__ union {
    struct { unsigned short sX[2][16 * 128]; unsigned short sP[2][64 * 128]; } g;  // 40KB (GEMM)
    struct { unsigned short sI[16 * 128]; unsigned short sJ[64 * 128];
             float nI[16]; float nJ[64]; } d;                                      // 20.3KB (dist)
  } sm;

  const int tid  = threadIdx.x;
  const int lane = tid & 63;
  const int w    = tid >> 6;          // wave 0..3

  // ---------------- Phase A: transpose+cast P ----------------
  if (tid < 32) {
    int id = blockIdx.x * 32 + tid;   // 0..16383
    int n  = id & 127;                // consecutive across lanes -> coalesced reads
    int kc = id >> 7;                 // chunk of 8 k
    union { unsigned short s[8]; uint4 v; } u;
#pragma unroll
    for (int j = 0; j < 8; ++j) u.s[j] = f2bf(P[(kc * 8 + j) * R_ + n]);
    *reinterpret_cast<uint4*>(&PbT[(size_t)n * D_ + kc * 8]) = u.v;
  }
  grid.sync();

  // ---------------- Phase B: T = X @ P ----------------
  {
    // XCD-bijective swizzle (512 % 8 == 0): consecutive logical blocks -> same XCD
    const int lb  = (blockIdx.x & 7) * 64 + (blockIdx.x >> 3);
    const int m0  = (lb >> 1) * 16;
    const int nb0 = (lb & 1) * 64;

    f32x4 acc;
    acc[0] = 0.f; acc[1] = 0.f; acc[2] = 0.f; acc[3] = 0.f;

    auto stage = [&](int buf, int kt) {
      const int k0 = kt * 128;
      // P: 1024 chunks of 16B (4/thread), linear LDS dest, inverse-swizzled global source
#pragma unroll
      for (int i = 0; i < 4; ++i) {
        int c = tid + 256 * i;
        int row = c >> 4, ch = c & 15;   // 16 chunks per 256B row
        gload_lds16(&PbT[(size_t)(nb0 + row) * D_ + k0 + ((ch ^ (row & 7)) * 8)],
                    reinterpret_cast<char*>(&sm.g.sP[buf][0]) + c * 16);
      }
      // X: 512 float4 chunks (2/thread), cvt->bf16x4, swizzled ds_write_b64
#pragma unroll
      for (int i = 0; i < 2; ++i) {
        int c = tid + 256 * i;
        int row = c >> 5;                // 0..15
        int kq  = (c & 31) * 4;          // float index 0..124
        float4 xv = *reinterpret_cast<const float4*>(&X[(size_t)(m0 + row) * D_ + k0 + kq]);
        uint2 p;
        p.x = (unsigned int)f2bf(xv.x) | ((unsigned int)f2bf(xv.y) << 16);
        p.y = (unsigned int)f2bf(xv.z) | ((unsigned int)f2bf(xv.w) << 16);
        int byte_in_row = (kq * 2) ^ ((row & 7) << 4);
        *reinterpret_cast<uint2*>(reinterpret_cast<char*>(&sm.g.sX[buf][0]) + row * 256 + byte_in_row) = p;
      }
    };

    auto compute = [&](int buf) {
      const char* xb = reinterpret_cast<const char*>(&sm.g.sX[buf][0]);
      const char* pb = reinterpret_cast<const char*>(&sm.g.sP[buf][0]);
#pragma unroll
      for (int s = 0; s < 4; ++s) {
        int koffb = s * 64 + ((lane >> 4) << 4);
        int ar = lane & 15;
        short8 a = *reinterpret_cast<const short8*>(xb + ar * 256 + (koffb ^ ((ar & 7) << 4)));
        int br = w * 16 + (lane & 15);
        short8 b = *reinterpret_cast<const short8*>(pb + br * 256 + (koffb ^ ((br & 7) << 4)));
        acc = __builtin_amdgcn_mfma_f32_16x16x32_bf16(a, b, acc, 0, 0, 0);
      }
    };

    stage(0, 0);
    __syncthreads();
    int buf = 0;
#pragma unroll
    for (int kt = 0; kt < 8; ++kt) {
      if (kt < 7) stage(buf ^ 1, kt + 1);
      compute(buf);
      __syncthreads();
      buf ^= 1;
    }

    const int col = lane & 15;
#pragma unroll
    for (int q = 0; q < 4; ++q) {
      int row = ((lane >> 4) << 2) + q;
      Tb[(size_t)(m0 + row) * R_ + nb0 + w * 16 + col] = f2bf(acc[q]);
    }
  }
  grid.sync();

  // ---------------- Phase C: Gram + distance epilogue (2 tiles/block) ----------------
#pragma unroll
  for (int half = 0; half < 2; ++half) {
    __syncthreads();   // previous tile's LDS reads done before restaging
    const int blk = half * 512 + blockIdx.x;   // 0..1023
    const int b   = blk >> 6;
    const int it  = (blk >> 2) & 15;
    const int jq  = blk & 3;

    // stage sI: 256 chunks of 16B (1/thread)
    {
      int row = tid >> 4, ch = tid & 15;
      gload_lds16(&Tb[(size_t)(b * L_ + it * 16 + row) * R_ + ((ch ^ (row & 7)) * 8)],
                  reinterpret_cast<char*>(sm.d.sI) + tid * 16);
    }
    // stage sJ: 1024 chunks (4/thread)
#pragma unroll
    for (int i = 0; i < 4; ++i) {
      int c = tid + 256 * i;
      int row = c >> 4, ch = c & 15;
      gload_lds16(&Tb[(size_t)(b * L_ + jq * 64 + row) * R_ + ((ch ^ (row & 7)) * 8)],
                  reinterpret_cast<char*>(sm.d.sJ) + c * 16);
    }
    __syncthreads();

    // norms from the staged (rounded) bf16 rows: threads 0..159, row = t>>1, half-row = t&1
    if (tid < 160) {
      int row = tid >> 1, h = tid & 1;
      const char* base = (row < 16) ? reinterpret_cast<const char*>(sm.d.sI)
                                    : reinterpret_cast<const char*>(sm.d.sJ);
      int r = (row < 16) ? row : row - 16;
      float s = 0.f;
#pragma unroll
      for (int j = 0; j < 8; ++j) {
        short8 v = *reinterpret_cast<const short8*>(base + r * 256 + ((h * 128 + j * 16) ^ ((r & 7) << 4)));
#pragma unroll
        for (int e = 0; e < 8; ++e) { float f = bf2f((unsigned short)v[e]); s += f * f; }
      }
      s += __shfl_xor(s, 1);
      if (h == 0) { if (row < 16) sm.d.nI[row] = s; else sm.d.nJ[row - 16] = s; }
    }

    // Gram via MFMA
    f32x4 acc;
    acc[0] = 0.f; acc[1] = 0.f; acc[2] = 0.f; acc[3] = 0.f;
    const char* ib = reinterpret_cast<const char*>(sm.d.sI);
    const char* jb = reinterpret_cast<const char*>(sm.d.sJ);
#pragma unroll
    for (int s = 0; s < 4; ++s) {
      int koffb = s * 64 + ((lane >> 4) << 4);
      int ar = lane & 15;
      short8 a = *reinterpret_cast<const short8*>(ib + ar * 256 + (koffb ^ ((ar & 7) << 4)));
      int br = w * 16 + (lane & 15);
      short8 bv = *reinterpret_cast<const short8*>(jb + br * 256 + (koffb ^ ((br & 7) << 4)));
      acc = __builtin_amdgcn_mfma_f32_16x16x32_bf16(a, bv, acc, 0, 0, 0);
    }
    __syncthreads();   // nI/nJ visible to all

    const int col = lane & 15;
    const int jj = w * 16 + col;
    const float nj = sm.d.nJ[jj];
#pragma unroll
    for (int q = 0; q < 4; ++q) {
      int ir = ((lane >> 4) << 2) + q;
      float v = sm.d.nI[ir] + nj - 2.0f * acc[q];
      Out[(size_t)(b * L_ + it * 16 + ir) * L_ + jq * 64 + jj] = fmaxf(v, 0.0f);
    }
  }
}

extern "C" void kernel_launch(void* const* d_in, const int* in_sizes, int n_in,
                              void* d_out, int out_size, void* d_ws, size_t ws_size,
                              hipStream_t stream) {
  const float* X = (const float*)d_in[0];   // [16,256,1024]
  const float* P = (const float*)d_in[1];   // [1024,128]
  float* Out = (float*)d_out;               // [16,256,256]
  char* ws = (char*)d_ws;
  unsigned short* PbT = (unsigned short*)ws;                               // 256 KB
  unsigned short* Tb  = (unsigned short*)(ws + (size_t)R_ * D_ * 2);       // 1 MB

  void* args[] = { (void*)&X, (void*)&P, (void*)&Out, (void*)&PbT, (void*)&Tb };
  hipLaunchCooperativeKernel((const void*)fused_all, dim3(512), dim3(256),
                             args, 0, stream);
}

// Round 5
// 121.740 us; speedup vs baseline: 1.0959x; 1.0959x over previous
//
#include <hip/hip_runtime.h>
#include <stdint.h>

#define B_ 16
#define L_ 256
#define D_ 1024
#define R_ 128
#define M_ (B_*L_)   // 4096 rows of t

typedef short short8 __attribute__((ext_vector_type(8)));
typedef float f32x4 __attribute__((ext_vector_type(4)));

__device__ __forceinline__ unsigned short f2bf(float f) {
  union { float f; unsigned int u; } v; v.f = f;
  unsigned int r = v.u + 0x7FFFu + ((v.u >> 16) & 1u);  // RNE
  return (unsigned short)(r >> 16);
}
__device__ __forceinline__ float bf2f(unsigned short s) {
  union { unsigned int u; float f; } v; v.u = ((unsigned int)s) << 16;
  return v.f;
}
__device__ __forceinline__ void gload_lds16(const void* g, void* l) {
  __builtin_amdgcn_global_load_lds(
      (const __attribute__((address_space(1))) unsigned int*)g,
      (__attribute__((address_space(3))) unsigned int*)l, 16, 0, 0);
}

// One kernel, phases chained by acyclic dataflow flags (no grid barrier):
//   A: P -> PbT (bf16, transposed); block g produces k-slice g>>6, releases scnt[g>>6]
//   B: T = X @ P (BM=16/BN=64/BK=128 dbuf); waits scnt[kt] before staging step kt;
//      releases bcnt[batch] after writing its T tile
//   C: Gram + distance epilogue (2 tiles/block); waits bcnt[b]==32 before staging
__global__ __launch_bounds__(256) void fused_flags(
    const float* __restrict__ X, const float* __restrict__ P,
    float* __restrict__ Out, unsigned short* __restrict__ PbT,
    unsigned short* __restrict__ Tb, unsigned int* __restrict__ scnt,
    unsigned int* __restrict__ bcnt) {

  __shared__ union {
    struct { unsigned short sX[2][16 * 128]; unsigned short sP[2][64 * 128]; } g;  // 40KB
    struct { unsigned short sI[16 * 128]; unsigned short sJ[64 * 128];
             float nI[16]; float nJ[64]; } d;                                      // 20.3KB
  } sm;

  const int tid  = threadIdx.x;
  const int lane = tid & 63;
  const int w    = tid >> 6;          // wave 0..3

  // consumer-side wait: tid0 relaxed-polls, one acquire load, block barrier
  auto wflag = [&](unsigned int* cell, unsigned int tgt) {
    if (tid == 0) {
      int guard = 0;
      while (__hip_atomic_load(cell, __ATOMIC_RELAXED, __HIP_MEMORY_SCOPE_AGENT) < tgt) {
        __builtin_amdgcn_s_sleep(1);
        if (++guard > (1 << 24)) break;   // bounded: never hangs
      }
      (void)__hip_atomic_load(cell, __ATOMIC_ACQUIRE, __HIP_MEMORY_SCOPE_AGENT);
    }
    __syncthreads();
  };

  // ---------------- Phase A: transpose+cast P (32 ids/block) ----------------
  if (tid < 32) {
    int id = blockIdx.x * 32 + tid;   // 0..16383
    int n  = id & 127;                // consecutive across lanes -> coalesced reads
    int kc = id >> 7;                 // chunk of 8 k; block g covers kc = g>>2
    union { unsigned short s[8]; uint4 v; } u;
#pragma unroll
    for (int j = 0; j < 8; ++j) u.s[j] = f2bf(P[(kc * 8 + j) * R_ + n]);
    *reinterpret_cast<uint4*>(&PbT[(size_t)n * D_ + kc * 8]) = u.v;
  }
  __syncthreads();   // drains vmcnt -> A stores in L2
  if (tid == 0)
    __hip_atomic_fetch_add(&scnt[blockIdx.x >> 6], 1,
                           __ATOMIC_RELEASE, __HIP_MEMORY_SCOPE_AGENT);

  // ---------------- Phase B: T = X @ P ----------------
  // XCD-bijective swizzle (512 % 8 == 0): consecutive logical blocks -> same XCD
  const int lb  = (blockIdx.x & 7) * 64 + (blockIdx.x >> 3);
  const int m0  = (lb >> 1) * 16;
  const int nb0 = (lb & 1) * 64;

  f32x4 acc;
  acc[0] = 0.f; acc[1] = 0.f; acc[2] = 0.f; acc[3] = 0.f;

  auto stageX = [&](int buf, int kt) {
    const int k0 = kt * 128;
    // X: 512 float4 chunks (2/thread), cvt->bf16x4, swizzled ds_write_b64
#pragma unroll
    for (int i = 0; i < 2; ++i) {
      int c = tid + 256 * i;
      int row = c >> 5;                // 0..15
      int kq  = (c & 31) * 4;          // float index 0..124
      float4 xv = *reinterpret_cast<const float4*>(&X[(size_t)(m0 + row) * D_ + k0 + kq]);
      uint2 p;
      p.x = (unsigned int)f2bf(xv.x) | ((unsigned int)f2bf(xv.y) << 16);
      p.y = (unsigned int)f2bf(xv.z) | ((unsigned int)f2bf(xv.w) << 16);
      int byte_in_row = (kq * 2) ^ ((row & 7) << 4);
      *reinterpret_cast<uint2*>(reinterpret_cast<char*>(&sm.g.sX[buf][0]) + row * 256 + byte_in_row) = p;
    }
  };
  auto stageP = [&](int buf, int kt) {
    const int k0 = kt * 128;
    // P: 1024 chunks of 16B (4/thread), linear LDS dest, inverse-swizzled global source
#pragma unroll
    for (int i = 0; i < 4; ++i) {
      int c = tid + 256 * i;
      int row = c >> 4, ch = c & 15;   // 16 chunks per 256B row
      gload_lds16(&PbT[(size_t)(nb0 + row) * D_ + k0 + ((ch ^ (row & 7)) * 8)],
                  reinterpret_cast<char*>(&sm.g.sP[buf][0]) + c * 16);
    }
  };
  auto compute = [&](int buf) {
    const char* xb = reinterpret_cast<const char*>(&sm.g.sX[buf][0]);
    const char* pb = reinterpret_cast<const char*>(&sm.g.sP[buf][0]);
#pragma unroll
    for (int s = 0; s < 4; ++s) {
      int koffb = s * 64 + ((lane >> 4) << 4);
      int ar = lane & 15;
      short8 a = *reinterpret_cast<const short8*>(xb + ar * 256 + (koffb ^ ((ar & 7) << 4)));
      int br = w * 16 + (lane & 15);
      short8 b = *reinterpret_cast<const short8*>(pb + br * 256 + (koffb ^ ((br & 7) << 4)));
      acc = __builtin_amdgcn_mfma_f32_16x16x32_bf16(a, b, acc, 0, 0, 0);
    }
  };

  stageX(0, 0);                 // X staging needs no PbT -> overlaps A completion
  wflag(&scnt[0], 64);
  stageP(0, 0);
  __syncthreads();
  int buf = 0;
  for (int kt = 0; kt < 8; ++kt) {
    if (kt < 7) {
      wflag(&scnt[kt + 1], 64); // instant after kt=0 (A long finished)
      stageP(buf ^ 1, kt + 1);
      stageX(buf ^ 1, kt + 1);
    }
    compute(buf);
    __syncthreads();
    buf ^= 1;
  }

  {
    const int col = lane & 15;
#pragma unroll
    for (int q = 0; q < 4; ++q) {
      int row = ((lane >> 4) << 2) + q;
      Tb[(size_t)(m0 + row) * R_ + nb0 + w * 16 + col] = f2bf(acc[q]);
    }
  }
  __syncthreads();   // all T-tile stores drained to L2
  if (tid == 0)
    __hip_atomic_fetch_add(&bcnt[lb >> 5], 1,
                           __ATOMIC_RELEASE, __HIP_MEMORY_SCOPE_AGENT);

  // ---------------- Phase C: Gram + distance epilogue (2 tiles/block) ----------------
#pragma unroll
  for (int half = 0; half < 2; ++half) {
    const int blk = half * 512 + blockIdx.x;   // 0..1023
    const int b   = blk >> 6;
    const int it  = (blk >> 2) & 15;
    const int jq  = blk & 3;

    wflag(&bcnt[b], 32);   // batch b's 32 producer tiles done (also guards LDS reuse)

    // stage sI: 256 chunks of 16B (1/thread)
    {
      int row = tid >> 4, ch = tid & 15;
      gload_lds16(&Tb[(size_t)(b * L_ + it * 16 + row) * R_ + ((ch ^ (row & 7)) * 8)],
                  reinterpret_cast<char*>(sm.d.sI) + tid * 16);
    }
    // stage sJ: 1024 chunks (4/thread)
#pragma unroll
    for (int i = 0; i < 4; ++i) {
      int c = tid + 256 * i;
      int row = c >> 4, ch = c & 15;
      gload_lds16(&Tb[(size_t)(b * L_ + jq * 64 + row) * R_ + ((ch ^ (row & 7)) * 8)],
                  reinterpret_cast<char*>(sm.d.sJ) + c * 16);
    }
    __syncthreads();

    // norms from the staged (rounded) bf16 rows: threads 0..159, row = t>>1, half-row = t&1
    if (tid < 160) {
      int row = tid >> 1, h = tid & 1;
      const char* base = (row < 16) ? reinterpret_cast<const char*>(sm.d.sI)
                                    : reinterpret_cast<const char*>(sm.d.sJ);
      int r = (row < 16) ? row : row - 16;
      float s = 0.f;
#pragma unroll
      for (int j = 0; j < 8; ++j) {
        short8 v = *reinterpret_cast<const short8*>(base + r * 256 + ((h * 128 + j * 16) ^ ((r & 7) << 4)));
#pragma unroll
        for (int e = 0; e < 8; ++e) { float f = bf2f((unsigned short)v[e]); s += f * f; }
      }
      s += __shfl_xor(s, 1);
      if (h == 0) { if (row < 16) sm.d.nI[row] = s; else sm.d.nJ[row - 16] = s; }
    }

    // Gram via MFMA
    f32x4 gac;
    gac[0] = 0.f; gac[1] = 0.f; gac[2] = 0.f; gac[3] = 0.f;
    const char* ib = reinterpret_cast<const char*>(sm.d.sI);
    const char* jb = reinterpret_cast<const char*>(sm.d.sJ);
#pragma unroll
    for (int s = 0; s < 4; ++s) {
      int koffb = s * 64 + ((lane >> 4) << 4);
      int ar = lane & 15;
      short8 a = *reinterpret_cast<const short8*>(ib + ar * 256 + (koffb ^ ((ar & 7) << 4)));
      int br = w * 16 + (lane & 15);
      short8 bv = *reinterpret_cast<const short8*>(jb + br * 256 + (koffb ^ ((br & 7) << 4)));
      gac = __builtin_amdgcn_mfma_f32_16x16x32_bf16(a, bv, gac, 0, 0, 0);
    }
    __syncthreads();   // nI/nJ visible to all

    const int col = lane & 15;
    const int jj = w * 16 + col;
    const float nj = sm.d.nJ[jj];
#pragma unroll
    for (int q = 0; q < 4; ++q) {
      int ir = ((lane >> 4) << 2) + q;
      float v = sm.d.nI[ir] + nj - 2.0f * gac[q];
      Out[(size_t)(b * L_ + it * 16 + ir) * L_ + jq * 64 + jj] = fmaxf(v, 0.0f);
    }
  }
}

extern "C" void kernel_launch(void* const* d_in, const int* in_sizes, int n_in,
                              void* d_out, int out_size, void* d_ws, size_t ws_size,
                              hipStream_t stream) {
  const float* X = (const float*)d_in[0];   // [16,256,1024]
  const float* P = (const float*)d_in[1];   // [1024,128]
  float* Out = (float*)d_out;               // [16,256,256]
  char* ws = (char*)d_ws;
  unsigned short* PbT = (unsigned short*)ws;                               // 256 KB
  unsigned short* Tb  = (unsigned short*)(ws + (size_t)R_ * D_ * 2);       // 1 MB
  unsigned int* scnt  = (unsigned int*)(ws + 0x140000);                    // 8 cells
  unsigned int* bcnt  = scnt + 8;                                          // 16 cells

  hipMemsetAsync(scnt, 0, 128, stream);     // zero flags every call (graph node)
  fused_flags<<<512, 256, 0, stream>>>(X, P, Out, PbT, Tb, scnt, bcnt);
}

// Round 7
// 20.829 us; speedup vs baseline: 6.4049x; 5.8447x over previous
//
#include <hip/hip_runtime.h>
#include <stdint.h>

#define B_ 16
#define L_ 256
#define D_ 1024
#define R_ 128
#define M_ (B_*L_)   // 4096 rows of t

typedef short short8 __attribute__((ext_vector_type(8)));
typedef float f32x4 __attribute__((ext_vector_type(4)));

__device__ __forceinline__ unsigned short f2bf(float f) {
  union { float f; unsigned int u; } v; v.f = f;
  unsigned int r = v.u + 0x7FFFu + ((v.u >> 16) & 1u);  // RNE
  return (unsigned short)(r >> 16);
}
__device__ __forceinline__ float bf2f(unsigned short s) {
  union { unsigned int u; float f; } v; v.u = ((unsigned int)s) << 16;
  return v.f;
}
__device__ __forceinline__ void gload_lds16(const void* g, void* l) {
  __builtin_amdgcn_global_load_lds(
      (const __attribute__((address_space(1))) unsigned int*)g,
      (__attribute__((address_space(3))) unsigned int*)l, 16, 0, 0);
}

// ---------------- K0: P [1024][128] f32 -> PbT [128][1024] bf16 ----------------
__global__ __launch_bounds__(256) void k0_transpose_cast(
    const float* __restrict__ P, unsigned short* __restrict__ PbT) {
  int id = blockIdx.x * 256 + threadIdx.x;   // 0..16383
  int n  = id & 127;                         // consecutive across lanes
  int kc = id >> 7;                          // chunk of 8 k
  union { unsigned short s[8]; uint4 v; } u;
#pragma unroll
  for (int j = 0; j < 8; ++j) u.s[j] = f2bf(P[(kc * 8 + j) * R_ + n]);
  *reinterpret_cast<uint4*>(&PbT[(size_t)n * D_ + kc * 8]) = u.v;
}

// ---------------- K1: t = X @ P  (bf16 MFMA) ----------------
// BM=16, BN=64, BK=128. grid=512, 2 blocks/CU.
// Counted-vmcnt pipeline, race-free placement: ALL staging into buf^1 happens
// AFTER barrier@kt (which guarantees every wave finished reading buf^1 at kt-1).
// Per-iter order: waitcnt(vmcnt 2, lgkm 0) -> barrier -> compute(buf)
//                 -> issueP(buf^1) -> loadX(kt+2) -> writeX(buf^1).
__global__ __launch_bounds__(256) void k1_gemm(
    const float* __restrict__ X, const unsigned short* __restrict__ PbT,
    unsigned short* __restrict__ Tb) {
  __shared__ unsigned short sX[2][16 * 128];    // 16 rows x 256B, swizzled  (8KB)
  __shared__ unsigned short sP[2][64 * 128];    // 64 rows x 256B, swizzled  (32KB)

  const int tid  = threadIdx.x;
  const int lane = tid & 63;
  const int w    = tid >> 6;          // wave 0..3
  // XCD-bijective swizzle (512 % 8 == 0)
  const int lb   = (blockIdx.x & 7) * 64 + (blockIdx.x >> 3);
  const int m0   = (lb >> 1) * 16;
  const int nb0  = (lb & 1) * 64;

  f32x4 acc;
  acc[0] = 0.f; acc[1] = 0.f; acc[2] = 0.f; acc[3] = 0.f;

  float4 xs[2][2];   // 2 prefetch slots x 2 chunks (statically indexed under unroll)

  auto loadX = [&](float4* slot, int kt) {
#pragma unroll
    for (int i = 0; i < 2; ++i) {
      int c = tid + 256 * i;
      int row = c >> 5, kq = (c & 31) * 4;
      slot[i] = *reinterpret_cast<const float4*>(&X[(size_t)(m0 + row) * D_ + kt * 128 + kq]);
    }
  };
  auto writeX = [&](int buf, const float4* slot) {
#pragma unroll
    for (int i = 0; i < 2; ++i) {
      int c = tid + 256 * i;
      int row = c >> 5, kq = (c & 31) * 4;
      uint2 p;
      p.x = (unsigned int)f2bf(slot[i].x) | ((unsigned int)f2bf(slot[i].y) << 16);
      p.y = (unsigned int)f2bf(slot[i].z) | ((unsigned int)f2bf(slot[i].w) << 16);
      int byte_in_row = (kq * 2) ^ ((row & 7) << 4);
      *reinterpret_cast<uint2*>(reinterpret_cast<char*>(&sX[buf][0]) + row * 256 + byte_in_row) = p;
    }
  };
  auto issueP = [&](int buf, int kt) {
    const int k0 = kt * 128;
#pragma unroll
    for (int i = 0; i < 4; ++i) {
      int c = tid + 256 * i;
      int row = c >> 4, ch = c & 15;   // 16 chunks per 256B row
      gload_lds16(&PbT[(size_t)(nb0 + row) * D_ + k0 + ((ch ^ (row & 7)) * 8)],
                  reinterpret_cast<char*>(&sP[buf][0]) + c * 16);
    }
  };
  auto compute = [&](int buf) {
    const char* xb = reinterpret_cast<const char*>(&sX[buf][0]);
    const char* pb = reinterpret_cast<const char*>(&sP[buf][0]);
#pragma unroll
    for (int s = 0; s < 4; ++s) {
      int koffb = s * 64 + ((lane >> 4) << 4);
      int ar = lane & 15;
      short8 a = *reinterpret_cast<const short8*>(xb + ar * 256 + (koffb ^ ((ar & 7) << 4)));
      int br = w * 16 + (lane & 15);
      short8 b = *reinterpret_cast<const short8*>(pb + br * 256 + (koffb ^ ((br & 7) << 4)));
      acc = __builtin_amdgcn_mfma_f32_16x16x32_bf16(a, b, acc, 0, 0, 0);
    }
  };

  // prologue: issue X(0), P(0), X(1); write sX[0] (compiler counted-waits xs[0] only)
  loadX(xs[0], 0);
  issueP(0, 0);
  loadX(xs[1], 1);
  writeX(0, xs[0]);
  // outstanding here: P(0)x4, X(1)x2

#pragma unroll
  for (int kt = 0; kt < 8; ++kt) {
    const int buf = kt & 1;
    // retire P(kt) (4 oldest); keep X loads in flight; publish last iter's sX writes
    if (kt == 7) asm volatile("s_waitcnt vmcnt(0) lgkmcnt(0)" ::: "memory");
    else         asm volatile("s_waitcnt vmcnt(2) lgkmcnt(0)" ::: "memory");
    __builtin_amdgcn_sched_barrier(0);
    __builtin_amdgcn_s_barrier();
    compute(buf);
    // staging into buf^1: safe, all waves passed barrier@kt (readers of buf^1 done)
    if (kt < 7) issueP(buf ^ 1, kt + 1);
    if (kt < 6) loadX(xs[kt & 1], kt + 2);
    if (kt < 7) writeX(buf ^ 1, xs[(kt + 1) & 1]);
  }

  // epilogue: write bf16 t
  const int col = lane & 15;
#pragma unroll
  for (int q = 0; q < 4; ++q) {
    int row = ((lane >> 4) << 2) + q;
    Tb[(size_t)(m0 + row) * R_ + nb0 + w * 16 + col] = f2bf(acc[q]);
  }
}

// ---------------- K2: per-batch Gram + distance epilogue ----------------
// block = (b, i-tile it, j-quarter jq). grid=1024 -> 4 blocks/CU.
__global__ __launch_bounds__(256) void k2_gram(
    const unsigned short* __restrict__ Tb, float* __restrict__ Out) {
  __shared__ unsigned short sI[16 * 128];    // 4KB, swizzled 256B rows
  __shared__ unsigned short sJ[64 * 128];    // 16KB
  __shared__ float nI[16], nJ[64];

  const int tid  = threadIdx.x;
  const int lane = tid & 63;
  const int w    = tid >> 6;        // 0..3
  const int blk  = blockIdx.x;
  const int b    = blk >> 6;
  const int it   = (blk >> 2) & 15;
  const int jq   = blk & 3;

  // stage sI: 256 chunks of 16B (1/thread)
  {
    int row = tid >> 4, ch = tid & 15;
    gload_lds16(&Tb[(size_t)(b * L_ + it * 16 + row) * R_ + ((ch ^ (row & 7)) * 8)],
                reinterpret_cast<char*>(sI) + tid * 16);
  }
  // stage sJ: 1024 chunks (4/thread)
#pragma unroll
  for (int i = 0; i < 4; ++i) {
    int c = tid + 256 * i;
    int row = c >> 4, ch = c & 15;
    gload_lds16(&Tb[(size_t)(b * L_ + jq * 64 + row) * R_ + ((ch ^ (row & 7)) * 8)],
                reinterpret_cast<char*>(sJ) + c * 16);
  }
  __syncthreads();

  // norms: threads 0..159, row = t>>1 (0..15 -> sI, 16..79 -> sJ), half = t&1
  if (tid < 160) {
    int row = tid >> 1, h = tid & 1;
    const char* base = (row < 16) ? reinterpret_cast<const char*>(sI)
                                  : reinterpret_cast<const char*>(sJ);
    int r = (row < 16) ? row : row - 16;
    float s = 0.f;
#pragma unroll
    for (int j = 0; j < 8; ++j) {
      short8 v = *reinterpret_cast<const short8*>(base + r * 256 + ((h * 128 + j * 16) ^ ((r & 7) << 4)));
#pragma unroll
      for (int e = 0; e < 8; ++e) { float f = bf2f((unsigned short)v[e]); s += f * f; }
    }
    s += __shfl_xor(s, 1);
    if (h == 0) { if (row < 16) nI[row] = s; else nJ[row - 16] = s; }
  }

  // Gram via MFMA
  f32x4 acc;
  acc[0] = 0.f; acc[1] = 0.f; acc[2] = 0.f; acc[3] = 0.f;
  const char* ib = reinterpret_cast<const char*>(sI);
  const char* jb = reinterpret_cast<const char*>(sJ);
#pragma unroll
  for (int s = 0; s < 4; ++s) {
    int koffb = s * 64 + ((lane >> 4) << 4);
    int ar = lane & 15;
    short8 a = *reinterpret_cast<const short8*>(ib + ar * 256 + (koffb ^ ((ar & 7) << 4)));
    int br = w * 16 + (lane & 15);
    short8 bv = *reinterpret_cast<const short8*>(jb + br * 256 + (koffb ^ ((br & 7) << 4)));
    acc = __builtin_amdgcn_mfma_f32_16x16x32_bf16(a, bv, acc, 0, 0, 0);
  }
  __syncthreads();   // nI/nJ visible to all

  const int col = lane & 15;
  const int jj = w * 16 + col;
  const float nj = nJ[jj];
#pragma unroll
  for (int q = 0; q < 4; ++q) {
    int ir = ((lane >> 4) << 2) + q;
    float v = nI[ir] + nj - 2.0f * acc[q];
    Out[(size_t)(b * L_ + it * 16 + ir) * L_ + jq * 64 + jj] = fmaxf(v, 0.0f);
  }
}

extern "C" void kernel_launch(void* const* d_in, const int* in_sizes, int n_in,
                              void* d_out, int out_size, void* d_ws, size_t ws_size,
                              hipStream_t stream) {
  const float* X = (const float*)d_in[0];   // [16,256,1024]
  const float* P = (const float*)d_in[1];   // [1024,128]
  float* Out = (float*)d_out;               // [16,256,256]
  char* ws = (char*)d_ws;
  unsigned short* PbT = (unsigned short*)ws;                               // 256 KB
  unsigned short* Tb  = (unsigned short*)(ws + (size_t)R_ * D_ * 2);       // 1 MB

  k0_transpose_cast<<<64, 256, 0, stream>>>(P, PbT);
  k1_gemm<<<M_ / 16 * 2, 256, 0, stream>>>(X, PbT, Tb);
  k2_gram<<<B_ * 16 * 4, 256, 0, stream>>>(Tb, Out);
}